// Round 6
// baseline (266.706 us; speedup 1.0000x reference)
//
#include <hip/hip_runtime.h>
#include <hip/hip_bf16.h>

#define BB 4
#define CC 256
#define CI 128
#define NN 4096
#define LOG2E 1.44269504088896f

typedef _Float16 f16;
typedef __attribute__((ext_vector_type(8))) _Float16 f16x8;
typedef __attribute__((ext_vector_type(4))) float f32x4;

#define MFMA(a,b,c) __builtin_amdgcn_mfma_f32_16x16x32_f16(a,b,c,0,0,0)
#define LDS3(p) ((__attribute__((address_space(3))) void*)(p))
#define GL1(p)  ((const __attribute__((address_space(1))) void*)(p))

// DPP 16-lane butterfly reduce (1-cy VALU ops, no LDS pipe)
#define DPP_MAX(x, ctrl) { int _s=__float_as_int(x); \
    float _y=__int_as_float(__builtin_amdgcn_update_dpp(_s,_s,ctrl,0xF,0xF,false)); \
    x = fmaxf(x,_y); }
#define DPP_ADD(x, ctrl) { int _s=__float_as_int(x); \
    float _y=__int_as_float(__builtin_amdgcn_update_dpp(_s,_s,ctrl,0xF,0xF,false)); \
    x = x+_y; }
__device__ __forceinline__ float rowmax16(float x){
    DPP_MAX(x,0xB1) DPP_MAX(x,0x4E) DPP_MAX(x,0x141) DPP_MAX(x,0x140) return x;
}
__device__ __forceinline__ float rowsum16(float x){
    DPP_ADD(x,0xB1) DPP_ADD(x,0x4E) DPP_ADD(x,0x141) DPP_ADD(x,0x140) return x;
}

// ---------------- K0: cast weights to f16 (theta pre-scaled by log2e) ----------------
__global__ __launch_bounds__(256) void k0_cast(const float* tw, const float* pw,
                                               const float* gw, const float* Ww, f16* dst){
    int i = blockIdx.x*256 + threadIdx.x;          // 0..131071
    int j = i & 32767; int sel = i >> 15;
    const float* s = (sel==0)? tw : (sel==1)? pw : (sel==2)? gw : Ww;
    float v = s[j];
    if (sel==0) v *= LOG2E;
    dst[i] = (f16)v;
}

// ---------------- K1: transpose+cast x[b][c][n] -> xt[b][n][c] f16 ----------------
__global__ __launch_bounds__(256) void k1_xpose(const float* x, f16* xt){
    int nt = blockIdx.x, ct = blockIdx.y, b = blockIdx.z;
    __shared__ float tile[64][65];
    int t = threadIdx.x;
    const float* src = x + ((size_t)(b*CC + ct*64))*NN + nt*64;
    #pragma unroll
    for (int k=0;k<16;k++){ int idx=t+k*256; int cl=idx>>6, nl=idx&63;
        tile[cl][nl]=src[(size_t)cl*NN + nl]; }
    __syncthreads();
    f16* dst = xt + ((size_t)(b*NN + nt*64))*CC + ct*64;
    #pragma unroll
    for (int k=0;k<16;k++){ int idx=t+k*256; int nl=idx>>6, cl=idx&63;
        dst[(size_t)nl*CC + cl] = (f16)tile[cl][nl]; }
}

// ---------------- K2a: theta OR phi projection, 64 rows/block ----------------
__global__ __launch_bounds__(256) void k2a_proj(const f16* xt, const f16* thw, const f16* phw,
                                                const float* thb, const float* phb,
                                                f16* th, f16* ph){
    int b = blockIdx.y; int ntile = blockIdx.x; int mat = blockIdx.z;
    int wv = threadIdx.x>>6, lane = threadIdx.x&63, q=lane>>4, cc=lane&15;
    int n0 = ntile*64 + wv*16;
    f16x8 aq[8];
    const f16* ap = xt + ((size_t)(b*NN + n0 + cc))*CC + q*8;
    #pragma unroll
    for (int kk=0;kk<8;kk++) aq[kk] = *(const f16x8*)(ap + kk*32);
    const f16* w   = mat? phw : thw;
    const float* bias = mat? phb : thb;
    float bscale = mat? 1.f : LOG2E;
    f16* o = mat? ph : th;
    #pragma unroll 1
    for (int os=0;os<8;os++){
        f32x4 acc={0,0,0,0};
        const f16* wp = w + ((size_t)(os*16 + cc))*CC + q*8;
        #pragma unroll
        for (int kk=0;kk<8;kk++){
            f16x8 bf = *(const f16x8*)(wp + kk*32);
            acc = MFMA(aq[kk], bf, acc);
        }
        float bv = bias[os*16+cc]*bscale;
        #pragma unroll
        for (int r=0;r<4;r++)
            o[((size_t)(b*NN + n0 + 4*q + r))*CI + os*16 + cc] = (f16)(acc[r] + bv);
    }
}

// ---------------- K2b: g projection, o-half per z, TILED output gt2[b][mt][o][64] ----------------
__global__ __launch_bounds__(256) void k2b_g(const f16* xt, const f16* gwh, const float* gb, f16* gt2){
    int b = blockIdx.y; int mt = blockIdx.x; int oz = blockIdx.z;
    int wv=threadIdx.x>>6, lane=threadIdx.x&63, q=lane>>4, cc=lane&15;
    int obase = oz*64 + wv*16;
    f16x8 ag[8];
    const f16* ap = gwh + ((size_t)(obase + cc))*CC + q*8;
    #pragma unroll
    for (int kk=0;kk<8;kk++) ag[kk] = *(const f16x8*)(ap + kk*32);
    f32x4 acc[4];
    #pragma unroll
    for (int ms=0;ms<4;ms++) acc[ms]=(f32x4){0,0,0,0};
    #pragma unroll 1
    for (int kk=0;kk<8;kk++){
        #pragma unroll
        for (int ms=0;ms<4;ms++){
            f16x8 bf = *(const f16x8*)(xt + ((size_t)(b*NN + mt*64 + ms*16 + cc))*CC + kk*32 + q*8);
            acc[ms]=MFMA(ag[kk],bf,acc[ms]);
        }
    }
    #pragma unroll
    for (int r=0;r<4;r++){
        int orow = obase + 4*q + r;
        float bv = gb[orow];
        #pragma unroll
        for (int ms=0;ms<4;ms++)
            gt2[((size_t)(b*64 + mt))*8192 + orow*64 + ms*16 + cc] = (f16)(acc[ms][r] + bv);
    }
}

// ---------------- K3: flash attention, LDS-staged, key-split x4, log2-domain ----------------
__global__ __launch_bounds__(256, 2) void k3_attn(const f16* th, const f16* ph, const f16* gt2,
                                                  f16* ypart, float* ml){
    int qt = blockIdx.x;           // 32 q-tiles of 128 rows
    int sp = blockIdx.y;           // 4 key splits of 1024 keys
    int b  = blockIdx.z;           // 4 batches
    int wv=threadIdx.x>>6, lane=threadIdx.x&63, q=lane>>4, cc=lane&15;
    int qrow0 = qt*128 + wv*32;
    int kv0 = sp*1024;
    int sw  = (cc&7)<<4;

    __shared__ __align__(16) char ldsb[81920];
    char* phL = ldsb;                       // [2][16384] phi tiles [64 keys][256B], XOR-swizzled
    char* gtL = ldsb + 32768;               // [2][16384] gt tiles [128 o][128B], XOR-swizzled
    char* plw = ldsb + 65536 + wv*4096;     // per-wave P [32 rows][128B], XOR-swizzled

    f16x8 aq[2][4];
    #pragma unroll
    for (int rb=0;rb<2;rb++){
        const f16* thp = th + ((size_t)(b*NN + qrow0 + rb*16 + cc))*CI + q*8;
        #pragma unroll
        for (int kk=0;kk<4;kk++) aq[rb][kk] = *(const f16x8*)(thp + kk*32);
    }

    const char* phg = (const char*)(ph + (size_t)b*NN*CI);
    int ph_row = wv*16 + (lane>>4);          // + ch*4
    int ph_c   = (lane&15)*16;
    const char* gtg = (const char*)gt2 + (size_t)b*64*16384;
    int gt_flat = wv*4096 + lane*16;         // + ch*1024

    f32x4 yacc[2][8];
    #pragma unroll
    for (int rb=0;rb<2;rb++)
        #pragma unroll
        for (int os=0;os<8;os++) yacc[rb][os]=(f32x4){0,0,0,0};
    float m_run[2][4];
    f32x4 l_vec[2];
    #pragma unroll
    for (int rb=0;rb<2;rb++){
        l_vec[rb]=(f32x4){0,0,0,0};
        #pragma unroll
        for (int r=0;r<4;r++) m_run[rb][r]=-1e30f;
    }

    // prologue: stage tile 0 into buffer 0
    {
        char* pbase = phL + wv*4096;
        char* gbase = gtL + wv*4096;
        #pragma unroll
        for (int ch=0; ch<4; ch++){
            int prow = ph_row + ch*4;
            const char* ps = phg + (size_t)(kv0 + prow)*256 + (ph_c ^ ((prow&7)<<4));
            __builtin_amdgcn_global_load_lds(GL1(ps), LDS3(pbase + ch*1024), 16, 0, 0);
            int gf = gt_flat + ch*1024;
            int grow = gf >> 7;
            const char* gs = gtg + (size_t)(sp*16)*16384 + grow*128 + ((gf&127) ^ ((grow&7)<<4));
            __builtin_amdgcn_global_load_lds(GL1(gs), LDS3(gbase + ch*1024), 16, 0, 0);
        }
    }
    __syncthreads();

    int cur = 0;
    #pragma unroll 1
    for (int it=0; it<16; ++it){
        if (it < 15){
            int m0n = kv0 + (it+1)*64;
            char* pbase = phL + (cur^1)*16384 + wv*4096;
            char* gbase = gtL + (cur^1)*16384 + wv*4096;
            #pragma unroll
            for (int ch=0; ch<4; ch++){
                int prow = ph_row + ch*4;
                const char* ps = phg + (size_t)(m0n + prow)*256 + (ph_c ^ ((prow&7)<<4));
                __builtin_amdgcn_global_load_lds(GL1(ps), LDS3(pbase + ch*1024), 16, 0, 0);
                int gf = gt_flat + ch*1024;
                int grow = gf >> 7;
                const char* gs = gtg + (size_t)(sp*16 + it+1)*16384 + grow*128 + ((gf&127) ^ ((grow&7)<<4));
                __builtin_amdgcn_global_load_lds(GL1(gs), LDS3(gbase + ch*1024), 16, 0, 0);
            }
        }
        const char* pt  = phL + cur*16384;
        const char* gtt = gtL + cur*16384;
        // QK^T (scores already in log2 domain: theta pre-scaled by log2e)
        f32x4 fa[2][4];
        #pragma unroll
        for (int j=0;j<4;j++){
            f16x8 pf[4];
            #pragma unroll
            for (int kk=0;kk<4;kk++)
                pf[kk] = *(const f16x8*)(pt + (j*16+cc)*256 + ((kk*64 + q*16) ^ sw));
            fa[0][j]=(f32x4){0,0,0,0}; fa[1][j]=(f32x4){0,0,0,0};
            #pragma unroll
            for (int kk=0;kk<4;kk++){
                fa[0][j]=MFMA(aq[0][kk], pf[kk], fa[0][j]);
                fa[1][j]=MFMA(aq[1][kk], pf[kk], fa[1][j]);
            }
        }
        // tile max per row via DPP; defer-max skip (THR=4 in log2 units)
        float mx[2][4]; float need = 0.f;
        #pragma unroll
        for (int rb=0;rb<2;rb++){
            #pragma unroll
            for (int r=0;r<4;r++){
                float m0 = fmaxf(fmaxf(fa[rb][0][r],fa[rb][1][r]), fmaxf(fa[rb][2][r],fa[rb][3][r]));
                m0 = rowmax16(m0);
                mx[rb][r]=m0;
                need = fmaxf(need, m0 - m_run[rb][r]);
            }
        }
        if (__any(need > 4.f)){
            #pragma unroll
            for (int rb=0;rb<2;rb++){
                #pragma unroll
                for (int r=0;r<4;r++){
                    float nm = fmaxf(m_run[rb][r], mx[rb][r]);
                    float co = exp2f(m_run[rb][r]-nm);
                    m_run[rb][r]=nm;
                    l_vec[rb][r]*=co;
                    #pragma unroll
                    for (int os=0;os<8;os++) yacc[rb][os][r]*=co;
                }
            }
        }
        #pragma unroll
        for (int rb=0;rb<2;rb++){
            #pragma unroll
            for (int j=0;j<4;j++){
                #pragma unroll
                for (int r=0;r<4;r++) fa[rb][j][r]=exp2f(fa[rb][j][r]-m_run[rb][r]);
            }
            #pragma unroll
            for (int r=0;r<4;r++)
                l_vec[rb][r] += (fa[rb][0][r]+fa[rb][1][r]) + (fa[rb][2][r]+fa[rb][3][r]);
        }
        // P scatter -> per-wave swizzled LDS [row=rb*16+4q+r][key]
        #pragma unroll
        for (int rb=0;rb<2;rb++){
            #pragma unroll
            for (int j=0;j<4;j++){
                #pragma unroll
                for (int r=0;r<4;r++){
                    *(f16*)(plw + (rb*16+4*q+r)*128 + (((j*16+cc)*2) ^ (((4*q+r)&7)<<4))) = (f16)fa[rb][j][r];
                }
            }
        }
        // PV
        #pragma unroll
        for (int kk2=0;kk2<2;kk2++){
            f16x8 pa0 = *(const f16x8*)(plw +  cc     *128 + ((q*16 + kk2*64) ^ sw));
            f16x8 pa1 = *(const f16x8*)(plw + (16+cc) *128 + ((q*16 + kk2*64) ^ sw));
            #pragma unroll
            for (int os=0;os<8;os++){
                f16x8 gv = *(const f16x8*)(gtt + (os*16+cc)*128 + ((kk2*64 + q*16) ^ sw));
                yacc[0][os] = MFMA(pa0, gv, yacc[0][os]);
                yacc[1][os] = MFMA(pa1, gv, yacc[1][os]);
            }
        }
        __syncthreads();
        cur ^= 1;
    }
    // reduce l across 16 lanes; write NORMALIZED partials + (m,l)
    float linv[2][4], lred[2][4];
    #pragma unroll
    for (int rb=0;rb<2;rb++)
        #pragma unroll
        for (int r=0;r<4;r++){
            float l = rowsum16(l_vec[rb][r]);
            lred[rb][r]=l; linv[rb][r]=1.f/l;
        }
    #pragma unroll
    for (int rb=0;rb<2;rb++){
        #pragma unroll
        for (int os=0;os<8;os++){
            #pragma unroll
            for (int r=0;r<4;r++)
                ypart[((size_t)((sp*4+b)*NN + qrow0 + rb*16 + 4*q + r))*CI + os*16 + cc] = (f16)(yacc[rb][os][r]*linv[rb][r]);
        }
    }
    if (cc==0){
        #pragma unroll
        for (int rb=0;rb<2;rb++){
            #pragma unroll
            for (int r=0;r<4;r++){
                size_t row = (size_t)(sp*4+b)*NN + qrow0 + rb*16 + 4*q + r;
                ml[row*2]   = m_run[rb][r];
                ml[row*2+1] = lred[rb][r];
            }
        }
    }
}

// ---------------- K3c: fused combine + Gram/mean stats (MFMA), 64 rows/block ----------------
__global__ __launch_bounds__(256) void k3c(const f16* ypart, const float* ml,
                                           f16* y, float* part, float* mupart){
    int blk = blockIdx.x; int t = threadIdx.x;     // 256 blocks
    int rloc = t>>2;                   // 0..63
    int row  = blk*64 + rloc;
    int b = row>>12, n = row & 4095;
    int o0 = (t&3)*32;
    __shared__ __align__(16) f16 ldsT[128*64];     // [o][n'] n-swizzled
    float m_s[4], l_s[4];
    #pragma unroll
    for (int s=0;s<4;s++){ size_t r2 = ((size_t)(s*4+b)*NN + n)*2; m_s[s]=ml[r2]; l_s[s]=ml[r2+1]; }
    float M = fmaxf(fmaxf(m_s[0],m_s[1]),fmaxf(m_s[2],m_s[3]));
    float w[4]; float L=0.f;
    #pragma unroll
    for (int s=0;s<4;s++){ w[s]=l_s[s]*exp2f(m_s[s]-M); L+=w[s]; }
    float inv = 1.f/L;
    #pragma unroll
    for (int s=0;s<4;s++) w[s]*=inv;
    float acc[32];
    #pragma unroll
    for (int j=0;j<32;j++) acc[j]=0.f;
    #pragma unroll
    for (int s=0;s<4;s++){
        const f16* src = ypart + ((size_t)(s*4+b)*NN + n)*CI + o0;
        #pragma unroll
        for (int v=0;v<4;v++){
            f16x8 vv = *(const f16x8*)(src + v*8);
            #pragma unroll
            for (int e=0;e<8;e++) acc[v*8+e] += w[s]*(float)vv[e];
        }
    }
    f16* yo = y + (size_t)row*CI + o0;
    #pragma unroll
    for (int v=0;v<4;v++){
        f16x8 ov;
        #pragma unroll
        for (int e=0;e<8;e++) ov[e] = (f16)acc[v*8+e];
        *(f16x8*)(yo + v*8) = ov;
        #pragma unroll
        for (int e=0;e<8;e++){
            int o = o0 + v*8 + e;
            ldsT[o*64 + (rloc ^ ((o&7)<<3))] = ov[e];
        }
    }
    __syncthreads();
    // Gram partial via MFMA over 64 rows: S_blk[o1][o2] = sum_n y[n][o1] y[n][o2]
    int wv=t>>6, lane=t&63, q=lane>>4, cc=lane&15;
    f32x4 gacc[2][8];
    #pragma unroll
    for (int a=0;a<2;a++)
        #pragma unroll
        for (int c2=0;c2<8;c2++) gacc[a][c2]=(f32x4){0,0,0,0};
    f16x8 af[2][2];
    #pragma unroll
    for (int o1t=0;o1t<2;o1t++){
        int o1 = (wv*2+o1t)*16+cc;
        #pragma unroll
        for (int kk=0;kk<2;kk++)
            af[o1t][kk] = *(const f16x8*)(ldsT + o1*64 + ((kk*32+q*8) ^ ((o1&7)<<3)));
    }
    #pragma unroll 1
    for (int o2t=0;o2t<8;o2t++){
        int o2 = o2t*16+cc;
        #pragma unroll
        for (int kk=0;kk<2;kk++){
            f16x8 bf = *(const f16x8*)(ldsT + o2*64 + ((kk*32+q*8) ^ ((o2&7)<<3)));
            gacc[0][o2t] = MFMA(af[0][kk], bf, gacc[0][o2t]);
            gacc[1][o2t] = MFMA(af[1][kk], bf, gacc[1][o2t]);
        }
    }
    float* pb = part + (size_t)blk*16384;
    #pragma unroll
    for (int o1t=0;o1t<2;o1t++){
        #pragma unroll
        for (int o2t=0;o2t<8;o2t++){
            #pragma unroll
            for (int r=0;r<4;r++)
                pb[((wv*2+o1t)*16+4*q+r)*128 + o2t*16+cc] = gacc[o1t][o2t][r];
        }
    }
    // mean partial
    if (t<128){
        float sm=0.f;
        #pragma unroll
        for (int v=0;v<8;v++){
            f16x8 vv = *(const f16x8*)(ldsT + t*64 + ((v*8) ^ ((t&7)<<3)));
            #pragma unroll
            for (int e=0;e<8;e++) sm += (float)vv[e];
        }
        mupart[blk*128 + t] = sm;
    }
}

// ---------------- K4b: reduce partials -> S[128*128], mu at S[16384..] ----------------
__global__ __launch_bounds__(256) void k4b_red(const float* part, const float* mupart, float* S){
    int blk = blockIdx.x; int t = threadIdx.x;
    if (blk < 64){
        int i = blk*256 + t;
        float s=0.f;
        #pragma unroll 1
        for (int p=0;p<256;p++) s += part[(size_t)p*16384 + i];
        S[i]=s;
    } else if (t < 128){
        float s=0.f;
        #pragma unroll 1
        for (int p=0;p<256;p++) s += mupart[p*128 + t];
        S[16384+t]=s;
    }
}

// ---------------- K4c: BN coefficients A[ch], B4[ch] ----------------
__global__ __launch_bounds__(128) void k4c_coef(const float* S, const float* Ww, const float* Wb,
                                                const float* gamma, const float* beta,
                                                const float* scale, float* AB){
    int ch = blockIdx.x; int t = threadIdx.x;
    const float* w = Ww + ch*CI;
    float tmp=0.f;
    const float* Srow = S + t*CI;
    #pragma unroll 1
    for (int o2=0;o2<CI;o2++) tmp += Srow[o2]*w[o2];
    float v  = w[t]*tmp;
    float mc = w[t]*S[16384 + t];
    #pragma unroll
    for (int s=1;s<64;s<<=1){ v += __shfl_xor(v,s); mc += __shfl_xor(mc,s); }
    __shared__ float red[4];
    if ((t&63)==0){ red[(t>>6)*2]=v; red[(t>>6)*2+1]=mc; }
    __syncthreads();
    if (t==0){
        float wSw = red[0]+red[2];
        float wmu = red[1]+red[3];
        const float M = 16384.f;
        float meanwy = wmu/M + Wb[ch];
        float var = wSw/M - (wmu/M)*(wmu/M);
        float inv = rsqrtf(var + 1e-5f);
        float sc = scale[0];
        float A  = sc*gamma[ch]*inv;
        float B3 = sc*(beta[ch] - meanwy*inv*gamma[ch]);
        AB[ch]     = A;
        AB[256+ch] = B3 + A*Wb[ch];
    }
}

// ---------------- K5: fused W-conv + BN + scale + residual, 512 blocks ----------------
__global__ __launch_bounds__(256) void k5_out(const f16* Wwh, const f16* y, const float* x,
                                              const float* AB, float* out){
    int ntile = blockIdx.x;      // 32
    int cht   = blockIdx.y;      // 4
    int b     = blockIdx.z;
    int wv=threadIdx.x>>6, lane=threadIdx.x&63, q=lane>>4, cc=lane&15;
    int ch0 = cht*64 + wv*16;
    f16x8 aw[4];
    const f16* wp = Wwh + ((size_t)(ch0+cc))*CI + q*8;
    #pragma unroll
    for (int kk=0;kk<4;kk++) aw[kk]=*(const f16x8*)(wp+kk*32);
    float Ar[4], Br[4];
    #pragma unroll
    for (int r=0;r<4;r++){ Ar[r]=AB[ch0+4*q+r]; Br[r]=AB[256+ch0+4*q+r]; }
    #pragma unroll 1
    for (int ns=0;ns<8;ns++){
        int n0 = ntile*128 + ns*16;
        f32x4 acc={0,0,0,0};
        const f16* yp = y + ((size_t)(b*NN + n0 + cc))*CI + q*8;
        #pragma unroll
        for (int kk=0;kk<4;kk++) acc = MFMA(aw[kk], *(const f16x8*)(yp+kk*32), acc);
        #pragma unroll
        for (int r=0;r<4;r++){
            size_t addr = ((size_t)(b*CC + ch0 + 4*q + r))*NN + n0 + cc;
            out[addr] = x[addr] + Ar[r]*acc[r] + Br[r];
        }
    }
}

extern "C" void kernel_launch(void* const* d_in, const int* in_sizes, int n_in,
                              void* d_out, int out_size, void* d_ws, size_t ws_size,
                              hipStream_t stream){
    const float* x    = (const float*)d_in[0];
    const float* g_w  = (const float*)d_in[1];
    const float* g_b  = (const float*)d_in[2];
    const float* th_w = (const float*)d_in[3];
    const float* th_b = (const float*)d_in[4];
    const float* ph_w = (const float*)d_in[5];
    const float* ph_b = (const float*)d_in[6];
    const float* W_w  = (const float*)d_in[7];
    const float* W_b  = (const float*)d_in[8];
    const float* bg   = (const float*)d_in[9];
    const float* bb   = (const float*)d_in[10];
    const float* sc   = (const float*)d_in[11];

    char* ws = (char*)d_ws;
    f16* xt  = (f16*)(ws);                                  // 8.4 MB
    f16* th  = (f16*)(ws + 8388608);                        // 4.2 MB
    f16* ph  = (f16*)(ws + 8388608 + 1*4194304);            // 4.2 MB
    f16* gt2 = (f16*)(ws + 8388608 + 2*4194304);            // 4.2 MB (tiled [b][mt][128][64])
    f16* y   = (f16*)(ws + 8388608 + 3*4194304);            // 4.2 MB
    f16* wh  = (f16*)(ws + 8388608 + 4*4194304);            // 256 KB
    float* ml    = (float*)(ws + 25427968);                 // 512 KB
    f16*   ypart = (f16*)(ws + 25952256);                   // 16.8 MB
    float* mupart= (float*)(ws + 42729472);                 // 128 KB
    float* part  = (float*)ws;                              // 16.8 MB overlay on xt+th+ph (dead after k3)
    float* S    = (float*)(ws + 42860544);                  // 66 KB
    float* AB   = (float*)(ws + 42926592);                  // 2 KB
    f16* th_wh = wh;
    f16* ph_wh = wh + 32768;
    f16* g_wh  = wh + 65536;
    f16* Ww_h  = wh + 98304;

    hipLaunchKernelGGL(k0_cast,  dim3(512),     dim3(256), 0, stream, th_w, ph_w, g_w, W_w, wh);
    hipLaunchKernelGGL(k1_xpose, dim3(64,4,4),  dim3(256), 0, stream, x, xt);
    hipLaunchKernelGGL(k2a_proj, dim3(64,4,2),  dim3(256), 0, stream, xt, th_wh, ph_wh, th_b, ph_b, th, ph);
    hipLaunchKernelGGL(k2b_g,    dim3(64,4,2),  dim3(256), 0, stream, xt, g_wh, g_b, gt2);
    hipLaunchKernelGGL(k3_attn,  dim3(32,4,4),  dim3(256), 0, stream, th, ph, gt2, ypart, ml);
    hipLaunchKernelGGL(k3c,      dim3(256),     dim3(256), 0, stream, ypart, ml, y, part, mupart);
    hipLaunchKernelGGL(k4b_red,  dim3(65),      dim3(256), 0, stream, part, mupart, S);
    hipLaunchKernelGGL(k4c_coef, dim3(256),     dim3(128), 0, stream, S, W_w, W_b, bg, bb, sc, AB);
    hipLaunchKernelGGL(k5_out,   dim3(32,4,4),  dim3(256), 0, stream, Ww_h, y, x, AB, (float*)d_out);
}

// Round 7
// 164.608 us; speedup vs baseline: 1.6202x; 1.6202x over previous
//
#include <hip/hip_runtime.h>
#include <hip/hip_bf16.h>

#define BB 4
#define CC 256
#define CI 128
#define NN 4096

typedef _Float16 f16;
typedef __attribute__((ext_vector_type(8))) _Float16 f16x8;
typedef __attribute__((ext_vector_type(4))) float f32x4;

#define MFMA(a,b,c) __builtin_amdgcn_mfma_f32_16x16x32_f16(a,b,c,0,0,0)
#define LDS3(p) ((__attribute__((address_space(3))) void*)(p))
#define GL1(p)  ((const __attribute__((address_space(1))) void*)(p))

// DPP 16-lane butterfly reduce (1-cy VALU ops, no LDS pipe)
#define DPP_MAX(x, ctrl) { int _s=__float_as_int(x); \
    float _y=__int_as_float(__builtin_amdgcn_update_dpp(_s,_s,ctrl,0xF,0xF,false)); \
    x = fmaxf(x,_y); }
#define DPP_ADD(x, ctrl) { int _s=__float_as_int(x); \
    float _y=__int_as_float(__builtin_amdgcn_update_dpp(_s,_s,ctrl,0xF,0xF,false)); \
    x = x+_y; }
__device__ __forceinline__ float rowmax16(float x){
    DPP_MAX(x,0xB1) DPP_MAX(x,0x4E) DPP_MAX(x,0x141) DPP_MAX(x,0x140) return x;
}
__device__ __forceinline__ float rowsum16(float x){
    DPP_ADD(x,0xB1) DPP_ADD(x,0x4E) DPP_ADD(x,0x141) DPP_ADD(x,0x140) return x;
}

// ---------------- K0: cast weights to f16 ----------------
__global__ __launch_bounds__(256) void k0_cast(const float* tw, const float* pw,
                                               const float* gw, const float* Ww, f16* dst){
    int i = blockIdx.x*256 + threadIdx.x;          // 0..131071
    int j = i & 32767; int sel = i >> 15;
    const float* s = (sel==0)? tw : (sel==1)? pw : (sel==2)? gw : Ww;
    dst[i] = (f16)s[j];
}

// ---------------- K1: transpose+cast x[b][c][n] -> xt[b][n][c] f16 ----------------
__global__ __launch_bounds__(256) void k1_xpose(const float* x, f16* xt){
    int nt = blockIdx.x, ct = blockIdx.y, b = blockIdx.z;
    __shared__ float tile[64][65];
    int t = threadIdx.x;
    const float* src = x + ((size_t)(b*CC + ct*64))*NN + nt*64;
    #pragma unroll
    for (int k=0;k<16;k++){ int idx=t+k*256; int cl=idx>>6, nl=idx&63;
        tile[cl][nl]=src[(size_t)cl*NN + nl]; }
    __syncthreads();
    f16* dst = xt + ((size_t)(b*NN + nt*64))*CC + ct*64;
    #pragma unroll
    for (int k=0;k<16;k++){ int idx=t+k*256; int nl=idx>>6, cl=idx&63;
        dst[(size_t)nl*CC + cl] = (f16)tile[cl][nl]; }
}

// ---------------- K2a: theta OR phi projection (z selects), 128 rows/block ----------------
__global__ __launch_bounds__(256) void k2a_proj(const f16* xt, const f16* thw, const f16* phw,
                                                const float* thb, const float* phb,
                                                f16* th, f16* ph){
    int b = blockIdx.y; int ntile = blockIdx.x; int mat = blockIdx.z;
    int wv = threadIdx.x>>6, lane = threadIdx.x&63, q=lane>>4, cc=lane&15;
    int n0 = ntile*128 + wv*32;
    f16x8 aq[2][8];
    #pragma unroll
    for (int ns=0;ns<2;ns++){
        const f16* ap = xt + ((size_t)(b*NN + n0 + ns*16 + cc))*CC + q*8;
        #pragma unroll
        for (int kk=0;kk<8;kk++) aq[ns][kk] = *(const f16x8*)(ap + kk*32);
    }
    const f16* w   = mat? phw : thw;
    const float* bias = mat? phb : thb;
    f16* o = mat? ph : th;
    #pragma unroll 1
    for (int os=0;os<8;os++){
        f32x4 acc0={0,0,0,0}, acc1={0,0,0,0};
        const f16* wp = w + ((size_t)(os*16 + cc))*CC + q*8;
        #pragma unroll
        for (int kk=0;kk<8;kk++){
            f16x8 bf = *(const f16x8*)(wp + kk*32);
            acc0 = MFMA(aq[0][kk], bf, acc0);
            acc1 = MFMA(aq[1][kk], bf, acc1);
        }
        float bv = bias[os*16+cc];
        #pragma unroll
        for (int r=0;r<4;r++){
            o[((size_t)(b*NN + n0      + 4*q + r))*CI + os*16 + cc] = (f16)(acc0[r] + bv);
            o[((size_t)(b*NN + n0 + 16 + 4*q + r))*CI + os*16 + cc] = (f16)(acc1[r] + bv);
        }
    }
}

// ---------------- K2b: g projection, TILED output gt2[b][mt][o][64] ----------------
__global__ __launch_bounds__(256) void k2b_g(const f16* xt, const f16* gwh, const float* gb, f16* gt2){
    int b = blockIdx.y; int mt = blockIdx.x;              // 64 tiles x 64 m
    int wv=threadIdx.x>>6, lane=threadIdx.x&63, q=lane>>4, cc=lane&15;
    f16x8 ag[2][8];
    #pragma unroll
    for (int os=0;os<2;os++){
        const f16* ap = gwh + ((size_t)(wv*32 + os*16 + cc))*CC + q*8;
        #pragma unroll
        for (int kk=0;kk<8;kk++) ag[os][kk] = *(const f16x8*)(ap + kk*32);
    }
    f32x4 acc[2][4];
    #pragma unroll
    for (int os=0;os<2;os++){
        #pragma unroll
        for (int ms=0;ms<4;ms++) acc[os][ms]=(f32x4){0,0,0,0};
    }
    #pragma unroll 1
    for (int kk=0;kk<8;kk++){
        #pragma unroll
        for (int ms=0;ms<4;ms++){
            f16x8 bf = *(const f16x8*)(xt + ((size_t)(b*NN + mt*64 + ms*16 + cc))*CC + kk*32 + q*8);
            acc[0][ms]=MFMA(ag[0][kk],bf,acc[0][ms]);
            acc[1][ms]=MFMA(ag[1][kk],bf,acc[1][ms]);
        }
    }
    #pragma unroll
    for (int os=0;os<2;os++){
        #pragma unroll
        for (int r=0;r<4;r++){
            int orow = wv*32 + os*16 + 4*q + r;
            float bv = gb[orow];
            #pragma unroll
            for (int ms=0;ms<4;ms++)
                gt2[((size_t)(b*64 + mt))*8192 + orow*64 + ms*16 + cc] = (f16)(acc[os][ms][r] + bv);
        }
    }
}

// ---------------- K3: flash attention, LDS-staged, key-split x4 ----------------
// writes NORMALIZED split outputs + (m,l) per row.  (round-5 verbatim)
__global__ __launch_bounds__(256, 2) void k3_attn(const f16* th, const f16* ph, const f16* gt2,
                                                  f16* ypart, float* ml){
    int qt = blockIdx.x;           // 32 q-tiles of 128 rows
    int sp = blockIdx.y;           // 4 key splits of 1024 keys
    int b  = blockIdx.z;           // 4 batches
    int wv=threadIdx.x>>6, lane=threadIdx.x&63, q=lane>>4, cc=lane&15;
    int qrow0 = qt*128 + wv*32;
    int kv0 = sp*1024;
    int sw  = (cc&7)<<4;

    __shared__ __align__(16) char ldsb[81920];
    char* phL = ldsb;                       // [2][16384] phi tiles [64 keys][256B], XOR-swizzled
    char* gtL = ldsb + 32768;               // [2][16384] gt tiles [128 o][128B], XOR-swizzled
    char* plw = ldsb + 65536 + wv*4096;     // per-wave P [32 rows][128B], XOR-swizzled

    f16x8 aq[2][4];
    #pragma unroll
    for (int rb=0;rb<2;rb++){
        const f16* thp = th + ((size_t)(b*NN + qrow0 + rb*16 + cc))*CI + q*8;
        #pragma unroll
        for (int kk=0;kk<4;kk++) aq[rb][kk] = *(const f16x8*)(thp + kk*32);
    }

    const char* phg = (const char*)(ph + (size_t)b*NN*CI);
    int ph_row = wv*16 + (lane>>4);          // + ch*4
    int ph_c   = (lane&15)*16;
    const char* gtg = (const char*)gt2 + (size_t)b*64*16384;
    int gt_flat = wv*4096 + lane*16;         // + ch*1024

    f32x4 yacc[2][8];
    #pragma unroll
    for (int rb=0;rb<2;rb++)
        #pragma unroll
        for (int os=0;os<8;os++) yacc[rb][os]=(f32x4){0,0,0,0};
    float m_run[2][4];
    f32x4 l_vec[2];
    #pragma unroll
    for (int rb=0;rb<2;rb++){
        l_vec[rb]=(f32x4){0,0,0,0};
        #pragma unroll
        for (int r=0;r<4;r++) m_run[rb][r]=-1e30f;
    }

    // prologue: stage tile 0 into buffer 0
    {
        char* pbase = phL + wv*4096;
        char* gbase = gtL + wv*4096;
        #pragma unroll
        for (int ch=0; ch<4; ch++){
            int prow = ph_row + ch*4;
            const char* ps = phg + (size_t)(kv0 + prow)*256 + (ph_c ^ ((prow&7)<<4));
            __builtin_amdgcn_global_load_lds(GL1(ps), LDS3(pbase + ch*1024), 16, 0, 0);
            int gf = gt_flat + ch*1024;
            int grow = gf >> 7;
            const char* gs = gtg + (size_t)(sp*16)*16384 + grow*128 + ((gf&127) ^ ((grow&7)<<4));
            __builtin_amdgcn_global_load_lds(GL1(gs), LDS3(gbase + ch*1024), 16, 0, 0);
        }
    }
    __syncthreads();

    int cur = 0;
    #pragma unroll 1
    for (int it=0; it<16; ++it){
        if (it < 15){
            int m0n = kv0 + (it+1)*64;
            char* pbase = phL + (cur^1)*16384 + wv*4096;
            char* gbase = gtL + (cur^1)*16384 + wv*4096;
            #pragma unroll
            for (int ch=0; ch<4; ch++){
                int prow = ph_row + ch*4;
                const char* ps = phg + (size_t)(m0n + prow)*256 + (ph_c ^ ((prow&7)<<4));
                __builtin_amdgcn_global_load_lds(GL1(ps), LDS3(pbase + ch*1024), 16, 0, 0);
                int gf = gt_flat + ch*1024;
                int grow = gf >> 7;
                const char* gs = gtg + (size_t)(sp*16 + it+1)*16384 + grow*128 + ((gf&127) ^ ((grow&7)<<4));
                __builtin_amdgcn_global_load_lds(GL1(gs), LDS3(gbase + ch*1024), 16, 0, 0);
            }
        }
        const char* pt  = phL + cur*16384;
        const char* gtt = gtL + cur*16384;
        // QK^T
        f32x4 fa[2][4];
        #pragma unroll
        for (int j=0;j<4;j++){
            f16x8 pf[4];
            #pragma unroll
            for (int kk=0;kk<4;kk++)
                pf[kk] = *(const f16x8*)(pt + (j*16+cc)*256 + ((kk*64 + q*16) ^ sw));
            fa[0][j]=(f32x4){0,0,0,0}; fa[1][j]=(f32x4){0,0,0,0};
            #pragma unroll
            for (int kk=0;kk<4;kk++){
                fa[0][j]=MFMA(aq[0][kk], pf[kk], fa[0][j]);
                fa[1][j]=MFMA(aq[1][kk], pf[kk], fa[1][j]);
            }
        }
        // tile max per row via DPP; defer-max skip (THR=3)
        float mx[2][4]; float need = 0.f;
        #pragma unroll
        for (int rb=0;rb<2;rb++){
            #pragma unroll
            for (int r=0;r<4;r++){
                float m0 = fmaxf(fmaxf(fa[rb][0][r],fa[rb][1][r]), fmaxf(fa[rb][2][r],fa[rb][3][r]));
                m0 = rowmax16(m0);
                mx[rb][r]=m0;
                need = fmaxf(need, m0 - m_run[rb][r]);
            }
        }
        if (__any(need > 3.f)){
            #pragma unroll
            for (int rb=0;rb<2;rb++){
                #pragma unroll
                for (int r=0;r<4;r++){
                    float nm = fmaxf(m_run[rb][r], mx[rb][r]);
                    float co = __expf(m_run[rb][r]-nm);
                    m_run[rb][r]=nm;
                    l_vec[rb][r]*=co;
                    #pragma unroll
                    for (int os=0;os<8;os++) yacc[rb][os][r]*=co;
                }
            }
        }
        #pragma unroll
        for (int rb=0;rb<2;rb++){
            #pragma unroll
            for (int j=0;j<4;j++){
                #pragma unroll
                for (int r=0;r<4;r++) fa[rb][j][r]=__expf(fa[rb][j][r]-m_run[rb][r]);
            }
            #pragma unroll
            for (int r=0;r<4;r++)
                l_vec[rb][r] += (fa[rb][0][r]+fa[rb][1][r]) + (fa[rb][2][r]+fa[rb][3][r]);
        }
        // P scatter -> per-wave swizzled LDS [row=rb*16+4q+r][key]
        #pragma unroll
        for (int rb=0;rb<2;rb++){
            #pragma unroll
            for (int j=0;j<4;j++){
                #pragma unroll
                for (int r=0;r<4;r++){
                    *(f16*)(plw + (rb*16+4*q+r)*128 + (((j*16+cc)*2) ^ (((4*q+r)&7)<<4))) = (f16)fa[rb][j][r];
                }
            }
        }
        // PV
        #pragma unroll
        for (int kk2=0;kk2<2;kk2++){
            f16x8 pa0 = *(const f16x8*)(plw +  cc     *128 + ((q*16 + kk2*64) ^ sw));
            f16x8 pa1 = *(const f16x8*)(plw + (16+cc) *128 + ((q*16 + kk2*64) ^ sw));
            #pragma unroll
            for (int os=0;os<8;os++){
                f16x8 gv = *(const f16x8*)(gtt + (os*16+cc)*128 + ((kk2*64 + q*16) ^ sw));
                yacc[0][os] = MFMA(pa0, gv, yacc[0][os]);
                yacc[1][os] = MFMA(pa1, gv, yacc[1][os]);
            }
        }
        __syncthreads();
        cur ^= 1;
    }
    // reduce l across 16 lanes; write NORMALIZED partials + (m,l)
    float linv[2][4], lred[2][4];
    #pragma unroll
    for (int rb=0;rb<2;rb++)
        #pragma unroll
        for (int r=0;r<4;r++){
            float l = rowsum16(l_vec[rb][r]);
            lred[rb][r]=l; linv[rb][r]=1.f/l;
        }
    #pragma unroll
    for (int rb=0;rb<2;rb++){
        #pragma unroll
        for (int os=0;os<8;os++){
            #pragma unroll
            for (int r=0;r<4;r++)
                ypart[((size_t)((sp*4+b)*NN + qrow0 + rb*16 + 4*q + r))*CI + os*16 + cc] = (f16)(yacc[rb][os][r]*linv[rb][r]);
        }
    }
    if (cc==0){
        #pragma unroll
        for (int rb=0;rb<2;rb++){
            #pragma unroll
            for (int r=0;r<4;r++){
                size_t row = (size_t)(sp*4+b)*NN + qrow0 + rb*16 + 4*q + r;
                ml[row*2]   = m_run[rb][r];
                ml[row*2+1] = lred[rb][r];
            }
        }
    }
}

// ---------------- K3c: fused combine + Gram/mean stats (MFMA), 64 rows/block, 256 blocks ----------------
__global__ __launch_bounds__(256) void k3c(const f16* ypart, const float* ml,
                                           f16* y, float* part, float* mupart){
    int blk = blockIdx.x; int t = threadIdx.x;     // 256 blocks
    int rloc = t>>2;                   // 0..63
    int row  = blk*64 + rloc;
    int b = row>>12, n = row & 4095;
    int o0 = (t&3)*32;
    __shared__ __align__(16) f16 ldsT[128*64];     // [o][n'] n-swizzled
    float m_s[4], l_s[4];
    #pragma unroll
    for (int s=0;s<4;s++){ size_t r2 = ((size_t)(s*4+b)*NN + n)*2; m_s[s]=ml[r2]; l_s[s]=ml[r2+1]; }
    float M = fmaxf(fmaxf(m_s[0],m_s[1]),fmaxf(m_s[2],m_s[3]));
    float w[4]; float L=0.f;
    #pragma unroll
    for (int s=0;s<4;s++){ w[s]=l_s[s]*__expf(m_s[s]-M); L+=w[s]; }
    float inv = 1.f/L;
    #pragma unroll
    for (int s=0;s<4;s++) w[s]*=inv;
    float acc[32];
    #pragma unroll
    for (int j=0;j<32;j++) acc[j]=0.f;
    #pragma unroll
    for (int s=0;s<4;s++){
        const f16* src = ypart + ((size_t)(s*4+b)*NN + n)*CI + o0;
        #pragma unroll
        for (int v=0;v<4;v++){
            f16x8 vv = *(const f16x8*)(src + v*8);
            #pragma unroll
            for (int e=0;e<8;e++) acc[v*8+e] += w[s]*(float)vv[e];
        }
    }
    f16* yo = y + (size_t)row*CI + o0;
    #pragma unroll
    for (int v=0;v<4;v++){
        f16x8 ov;
        #pragma unroll
        for (int e=0;e<8;e++) ov[e] = (f16)acc[v*8+e];
        *(f16x8*)(yo + v*8) = ov;
        #pragma unroll
        for (int e=0;e<8;e++){
            int o = o0 + v*8 + e;
            ldsT[o*64 + (rloc ^ ((o&7)<<3))] = ov[e];
        }
    }
    __syncthreads();
    // Gram partial via MFMA over 64 rows: S_blk[o1][o2] = sum_n y[n][o1] y[n][o2]
    int wv=t>>6, lane=t&63, q=lane>>4, cc=lane&15;
    f32x4 gacc[2][8];
    #pragma unroll
    for (int a=0;a<2;a++)
        #pragma unroll
        for (int c2=0;c2<8;c2++) gacc[a][c2]=(f32x4){0,0,0,0};
    f16x8 af[2][2];
    #pragma unroll
    for (int o1t=0;o1t<2;o1t++){
        int o1 = (wv*2+o1t)*16+cc;
        #pragma unroll
        for (int kk=0;kk<2;kk++)
            af[o1t][kk] = *(const f16x8*)(ldsT + o1*64 + ((kk*32+q*8) ^ ((o1&7)<<3)));
    }
    #pragma unroll 1
    for (int o2t=0;o2t<8;o2t++){
        int o2 = o2t*16+cc;
        #pragma unroll
        for (int kk=0;kk<2;kk++){
            f16x8 bf = *(const f16x8*)(ldsT + o2*64 + ((kk*32+q*8) ^ ((o2&7)<<3)));
            gacc[0][o2t] = MFMA(af[0][kk], bf, gacc[0][o2t]);
            gacc[1][o2t] = MFMA(af[1][kk], bf, gacc[1][o2t]);
        }
    }
    float* pb = part + (size_t)blk*16384;
    #pragma unroll
    for (int o1t=0;o1t<2;o1t++){
        #pragma unroll
        for (int o2t=0;o2t<8;o2t++){
            #pragma unroll
            for (int r=0;r<4;r++)
                pb[((wv*2+o1t)*16+4*q+r)*128 + o2t*16+cc] = gacc[o1t][o2t][r];
        }
    }
    // mean partial
    if (t<128){
        float sm=0.f;
        #pragma unroll
        for (int v=0;v<8;v++){
            f16x8 vv = *(const f16x8*)(ldsT + t*64 + ((v*8) ^ ((t&7)<<3)));
            #pragma unroll
            for (int e=0;e<8;e++) sm += (float)vv[e];
        }
        mupart[blk*128 + t] = sm;
    }
}

// ---------------- K4b: chunked reduce of partials -> atomicAdd into S (pre-zeroed) ----------------
__global__ __launch_bounds__(256) void k4b_red(const float* part, const float* mupart, float* S){
    int pc = blockIdx.y;               // 8 chunks of 32 partials
    int t = threadIdx.x;
    if (blockIdx.x < 64){
        int i = blockIdx.x*256 + t;
        float s=0.f;
        #pragma unroll 1
        for (int p=pc*32; p<pc*32+32; p++) s += part[(size_t)p*16384 + i];
        atomicAdd(&S[i], s);
    } else if (t < 128){
        float s=0.f;
        #pragma unroll 1
        for (int p=pc*32; p<pc*32+32; p++) s += mupart[p*128 + t];
        atomicAdd(&S[16384+t], s);
    }
}

// ---------------- K4c: BN coefficients A[ch], B4[ch] ----------------
__global__ __launch_bounds__(128) void k4c_coef(const float* S, const float* Ww, const float* Wb,
                                                const float* gamma, const float* beta,
                                                const float* scale, float* AB){
    int ch = blockIdx.x; int t = threadIdx.x;
    const float* w = Ww + ch*CI;
    float tmp=0.f;
    const float* Srow = S + t*CI;
    #pragma unroll 1
    for (int o2=0;o2<CI;o2++) tmp += Srow[o2]*w[o2];
    float v  = w[t]*tmp;
    float mc = w[t]*S[16384 + t];
    #pragma unroll
    for (int s=1;s<64;s<<=1){ v += __shfl_xor(v,s); mc += __shfl_xor(mc,s); }
    __shared__ float red[4];
    if ((t&63)==0){ red[(t>>6)*2]=v; red[(t>>6)*2+1]=mc; }
    __syncthreads();
    if (t==0){
        float wSw = red[0]+red[2];
        float wmu = red[1]+red[3];
        const float M = 16384.f;
        float meanwy = wmu/M + Wb[ch];
        float var = wSw/M - (wmu/M)*(wmu/M);
        float inv = rsqrtf(var + 1e-5f);
        float sc = scale[0];
        float A  = sc*gamma[ch]*inv;
        float B3 = sc*(beta[ch] - meanwy*inv*gamma[ch]);
        AB[ch]     = A;
        AB[256+ch] = B3 + A*Wb[ch];
    }
}

// ---------------- K5: fused W-conv + BN + scale + residual ----------------
__global__ __launch_bounds__(256) void k5_out(const f16* Wwh, const f16* y, const float* x,
                                              const float* AB, float* out){
    int ntile = blockIdx.x;      // 16
    int cht   = blockIdx.y;      // 4
    int b     = blockIdx.z;
    int wv=threadIdx.x>>6, lane=threadIdx.x&63, q=lane>>4, cc=lane&15;
    int ch0 = cht*64 + wv*16;
    f16x8 aw[4];
    const f16* wp = Wwh + ((size_t)(ch0+cc))*CI + q*8;
    #pragma unroll
    for (int kk=0;kk<4;kk++) aw[kk]=*(const f16x8*)(wp+kk*32);
    float Ar[4], Br[4];
    #pragma unroll
    for (int r=0;r<4;r++){ Ar[r]=AB[ch0+4*q+r]; Br[r]=AB[256+ch0+4*q+r]; }
    #pragma unroll 1
    for (int ns=0;ns<16;ns++){
        int n0 = ntile*256 + ns*16;
        f32x4 acc={0,0,0,0};
        const f16* yp = y + ((size_t)(b*NN + n0 + cc))*CI + q*8;
        #pragma unroll
        for (int kk=0;kk<4;kk++) acc = MFMA(aw[kk], *(const f16x8*)(yp+kk*32), acc);
        #pragma unroll
        for (int r=0;r<4;r++){
            size_t addr = ((size_t)(b*CC + ch0 + 4*q + r))*NN + n0 + cc;
            out[addr] = x[addr] + Ar[r]*acc[r] + Br[r];
        }
    }
}

extern "C" void kernel_launch(void* const* d_in, const int* in_sizes, int n_in,
                              void* d_out, int out_size, void* d_ws, size_t ws_size,
                              hipStream_t stream){
    const float* x    = (const float*)d_in[0];
    const float* g_w  = (const float*)d_in[1];
    const float* g_b  = (const float*)d_in[2];
    const float* th_w = (const float*)d_in[3];
    const float* th_b = (const float*)d_in[4];
    const float* ph_w = (const float*)d_in[5];
    const float* ph_b = (const float*)d_in[6];
    const float* W_w  = (const float*)d_in[7];
    const float* W_b  = (const float*)d_in[8];
    const float* bg   = (const float*)d_in[9];
    const float* bb   = (const float*)d_in[10];
    const float* sc   = (const float*)d_in[11];

    char* ws = (char*)d_ws;
    f16* xt  = (f16*)(ws);                                  // 8.4 MB
    f16* th  = (f16*)(ws + 8388608);                        // 4.2 MB
    f16* ph  = (f16*)(ws + 8388608 + 1*4194304);            // 4.2 MB
    f16* gt2 = (f16*)(ws + 8388608 + 2*4194304);            // 4.2 MB (tiled [b][mt][128][64])
    f16* y   = (f16*)(ws + 8388608 + 3*4194304);            // 4.2 MB
    f16* wh  = (f16*)(ws + 8388608 + 4*4194304);            // 256 KB
    float* ml    = (float*)(ws + 25427968);                 // 512 KB
    f16*   ypart = (f16*)(ws + 25952256);                   // 16.8 MB
    float* mupart= (float*)(ws + 42729472);                 // 128 KB
    float* part  = (float*)ws;                              // 16.8 MB overlay on xt+th+ph (dead after k3)
    float* S    = (float*)(ws + 42860544);                  // 66 KB
    float* AB   = (float*)(ws + 42926592);                  // 2 KB
    f16* th_wh = wh;
    f16* ph_wh = wh + 32768;
    f16* g_wh  = wh + 65536;
    f16* Ww_h  = wh + 98304;

    hipMemsetAsync(S, 0, 16512*sizeof(float), stream);
    hipLaunchKernelGGL(k0_cast,  dim3(512),     dim3(256), 0, stream, th_w, ph_w, g_w, W_w, wh);
    hipLaunchKernelGGL(k1_xpose, dim3(64,4,4),  dim3(256), 0, stream, x, xt);
    hipLaunchKernelGGL(k2a_proj, dim3(32,4,2),  dim3(256), 0, stream, xt, th_wh, ph_wh, th_b, ph_b, th, ph);
    hipLaunchKernelGGL(k2b_g,    dim3(64,4),    dim3(256), 0, stream, xt, g_wh, g_b, gt2);
    hipLaunchKernelGGL(k3_attn,  dim3(32,4,4),  dim3(256), 0, stream, th, ph, gt2, ypart, ml);
    hipLaunchKernelGGL(k3c,      dim3(256),     dim3(256), 0, stream, ypart, ml, y, part, mupart);
    hipLaunchKernelGGL(k4b_red,  dim3(65,8),    dim3(256), 0, stream, part, mupart, S);
    hipLaunchKernelGGL(k4c_coef, dim3(256),     dim3(128), 0, stream, S, W_w, W_b, bg, bb, sc, AB);
    hipLaunchKernelGGL(k5_out,   dim3(16,4,4),  dim3(256), 0, stream, Ww_h, y, x, AB, (float*)d_out);
}